// Round 11
// baseline (117.641 us; speedup 1.0000x reference)
//
#include <hip/hip_runtime.h>

// FrequencyAwareSpatialAttention via MFMA.
// R11: staging via global_load_lds DMA (zero-VGPR, deep queue) -> LDS x-tile,
// sobel reads LDS, writes bf16 frq (unpadded 289 rows + shared zero-row).
// R8-R10 proved the compiler pins register-staged loads at depth ~2-4
// (VGPR stuck at 52 through sched_barrier / LDS-pad / inline-asm attempts).
// Per block (one 17x17 window, 8 waves, 2 chunks of 32 channels):
//   DMA chunk -> barrier -> sobel(pk_fma + DPP shr/shl) -> barrier -> ...
//   conv 64->16 3x3: 9 offsets x 2 mfma_f32_16x16x32_bf16 (K=64), zero-row
//   for out-of-window taps; + b1, relu, 1x1 conv + b2, sigmoid, clip, store.

#define WSZ 17
#define NT  512           // 8 waves
#define CH  (510 * 510)   // floats per channel plane

typedef __attribute__((ext_vector_type(8))) short bf16x8;
typedef __attribute__((ext_vector_type(4))) float f32x4;
typedef __attribute__((ext_vector_type(2))) float f32x2;

// XOR swizzle: involution within each 128B frq row (row = pixel index).
__device__ __forceinline__ int swz(int off) {
    return off ^ (((off >> 7) & 7) << 4);
}

__device__ __forceinline__ unsigned short f2bf(float f) {
    union { float f; unsigned u; } v; v.f = f;
    unsigned u = v.u;
    unsigned r = u + 0x7fffu + ((u >> 16) & 1u);   // RNE
    return (unsigned short)(r >> 16);
}

// lane i <- lane i-1 (wave_shr:1), lane 0 <- 0
__device__ __forceinline__ float dpp_shr1(float v) {
    return __int_as_float(
        __builtin_amdgcn_update_dpp(0, __float_as_int(v), 0x138, 0xf, 0xf, true));
}
// lane i <- lane i+1 (wave_shl:1), lane 63 <- 0
__device__ __forceinline__ float dpp_shl1(float v) {
    return __int_as_float(
        __builtin_amdgcn_update_dpp(0, __float_as_int(v), 0x130, 0xf, 0xf, true));
}

// async global->LDS DMA, width 4: per-lane global src, dest = base + lane*4
typedef __attribute__((address_space(1))) const unsigned GU;
typedef __attribute__((address_space(3))) unsigned LU;
__device__ __forceinline__ void gl_lds(const float* g, char* l) {
    __builtin_amdgcn_global_load_lds((GU*)g, (LU*)l, 4, 0, 0);
}

// Pre-kernel: transpose+convert w1 [16][64][3][3] fp32 into A-fragment order.
// Fragment (dij, ks): lane l holds A[m = l&15][k = ks*32 + 8*(l>>4) + j], j=0..7.
__global__ void prep_w1(const float* __restrict__ w1, unsigned short* __restrict__ wt) {
    const int dij = blockIdx.x >> 1;
    const int ks  = blockIdx.x & 1;
    const int l   = threadIdx.x;           // 0..63
    const int m   = l & 15;
    const int kb  = ks * 32 + 8 * (l >> 4);
    bf16x8 v;
#pragma unroll
    for (int jj = 0; jj < 8; ++jj)
        v[jj] = (short)f2bf(w1[m * 576 + (kb + jj) * 9 + dij]);
    ((bf16x8*)wt)[blockIdx.x * 64 + l] = v;
}

__global__ __launch_bounds__(NT, 4)
void fasa_mfma(const float* __restrict__ x,
               const float* __restrict__ sobel_w,
               const unsigned short* __restrict__ wt,
               const float* __restrict__ b1,
               const float* __restrict__ w2,
               const float* __restrict__ b2,
               float* __restrict__ out)
{
    // x-chunk staging buffer (32 channels): main [c4][17 rows][4ch][16cols]
    __shared__ __align__(16) char xm[8 * 17 * 256];   // 34816 B
    __shared__ __align__(16) char xt[9 * 256];        // col-16 tail [i0][isub][c32]
    // frq: rows 0..288 = pixels (i*17+j), row 289 = shared zero row
    __shared__ __align__(16) char frq[290 * 128];     // 37120 B   (total 74240)

    const int t    = threadIdx.x;
    const int lane = t & 63;
    const int wave = __builtin_amdgcn_readfirstlane(t >> 6);

    // XCD-chunked swizzle (bijective, 3600 = 8*450)
    const int bid = blockIdx.x;
    const int win = (bid & 7) * 450 + (bid >> 3);   // b*900 + wh*30 + ww
    const int b   = win / 900;
    const int rem = win % 900;
    const int h0  = (rem / 30) * WSZ;
    const int w0  = (rem % 30) * WSZ;

    // zero row 289 of frq (the only zeroing needed)
    if (t < 8) *(f32x4*)(frq + 289 * 128 + t * 16) = (f32x4){0.f, 0.f, 0.f, 0.f};

    // sobel weights: all channels share one 3x3 (tiled in setup) -> scalar regs
    float sw[9];
#pragma unroll
    for (int k = 0; k < 9; ++k) sw[k] = sobel_w[k];

    const int j   = lane & 31;       // column, active when j < 17
    const int grp = lane >> 5;
    const bool jac = (j < 17);

    // per-lane DMA source offsets (constant across instructions)
    const float* xw = x + ((size_t)b * 64) * CH + (size_t)h0 * 510 + w0;
    const float* gm_base = xw + ((size_t)(wave * 4) + (lane >> 4)) * CH + (lane & 15);
    const float* gt_base = xw + ((size_t)(lane & 31)) * CH + (lane >> 5) * 510 + 16;

    // ---- DMA one 32-channel chunk into xm/xt ----
    auto DMA_CHUNK = [&](int q) {
        const float* gm = gm_base + (size_t)q * 32 * CH;
        char* dm = xm + wave * 17 * 256;
#pragma unroll
        for (int i = 0; i < 17; ++i)
            gl_lds(gm + i * 510, dm + i * 256);
        const float* gt = gt_base + (size_t)q * 32 * CH;
        gl_lds(gt + 2 * wave * 510, xt + wave * 256);   // i0 = wave
        if (wave == 7)                                   // i0 = 8: rows 16,16
            gl_lds(gt + (16 * 510 - (lane >> 5) * 510), xt + 8 * 256);
    };

    // ---- sobel one chunk: wave w, grp g -> pair (q*16 + 2w + g) ----
    auto SOBEL_CHUNK = [&](int q) {
        const int pr = q * 16 + 2 * wave + grp;       // global pair 0..31
        const bool j16 = (j == 16);
        const int mj = j > 15 ? 15 : j;
        const char* mb = xm + (wave * 17) * 256 + (2 * grp) * 64 + mj * 4;
        const char* tb = xt + (4 * wave + 2 * grp) * 4;
        const char* a0 = j16 ? tb : mb;
        const int st  = j16 ? 128 : 256;
        const int o2  = j16 ? 4   : 64;
        f32x2 xr[17];
#pragma unroll
        for (int i = 0; i < 17; ++i) {
            float v0 = *(const float*)(a0);
            float v1 = *(const float*)(a0 + o2);
            a0 += st;
            xr[i].x = jac ? v0 : 0.f;        // zero cols at j>=17 feed DPP pads
            xr[i].y = jac ? v1 : 0.f;
        }
#pragma unroll
        for (int i = 0; i < 17; ++i) {
            f32x2 top = (i > 0)  ? xr[i - 1] : (f32x2){0.f, 0.f};
            f32x2 mid = xr[i];
            f32x2 bot = (i < 16) ? xr[i + 1] : (f32x2){0.f, 0.f};
            f32x2 p0 = sw[0] * top + sw[3] * mid + sw[6] * bot;
            f32x2 p1 = sw[1] * top + sw[4] * mid + sw[7] * bot;
            f32x2 p2 = sw[2] * top + sw[5] * mid + sw[8] * bot;
            f32x2 o;
            o.x = p1.x + dpp_shr1(p0.x) + dpp_shl1(p2.x);
            o.y = p1.y + dpp_shr1(p0.y) + dpp_shl1(p2.y);
            unsigned pkv;
            asm("v_cvt_pk_bf16_f32 %0, %1, %2" : "=v"(pkv) : "v"(o.x), "v"(o.y));
            if (jac)
                *(unsigned*)(frq + swz((i * 17 + j) * 128 + pr * 4)) = pkv;
        }
    };

    DMA_CHUNK(0);
    asm volatile("s_waitcnt vmcnt(0)" ::: "memory");
    __syncthreads();
    SOBEL_CHUNK(0);
    __syncthreads();                 // all xbuf reads done before overwrite
    DMA_CHUNK(1);
    asm volatile("s_waitcnt vmcnt(0)" ::: "memory");
    __syncthreads();
    SOBEL_CHUNK(1);

    // ---- W fragments + epilogue constants (overlap the final barrier) ----
    bf16x8 wf[18];
#pragma unroll
    for (int i = 0; i < 18; ++i)
        wf[i] = ((const bf16x8*)wt)[i * 64 + lane];

    float b1v[4], w2v[4];
#pragma unroll
    for (int r = 0; r < 4; ++r) {
        int m = 4 * (lane >> 4) + r;
        b1v[r] = b1[m];
        w2v[r] = w2[m];
    }
    const float b2v = b2[0];

    __syncthreads();

    // ---- conv1 via MFMA: wave w handles pixel tiles {w, w+8, w+16} ----
    const int n   = lane & 15;          // pixel within tile (MFMA N)
    const int g16 = (lane >> 4) * 16;   // 8-channel chunk byte offset

#pragma unroll 1
    for (int nt = wave; nt < 19; nt += 8) {
        int p  = nt * 16 + n;
        int pv = p > 288 ? 288 : p;     // clamp dead lanes of last tile
        int pi = pv / 17, pj = pv - pi * 17;

        f32x4 acc = {0.f, 0.f, 0.f, 0.f};
#pragma unroll
        for (int d = 0; d < 9; ++d) {
            const int di = d / 3 - 1, dj = d % 3 - 1;      // compile-time
            bool ok = ((unsigned)(pi + di) < 17u) & ((unsigned)(pj + dj) < 17u);
            int row = ok ? (pv + di * 17 + dj) : 289;      // 289 = zero row
            int off = row * 128 + g16;
            bf16x8 bfA = *(const bf16x8*)(frq + swz(off));
            bf16x8 bfB = *(const bf16x8*)(frq + swz(off + 64));
            acc = __builtin_amdgcn_mfma_f32_16x16x32_bf16(wf[2 * d],     bfA, acc, 0, 0, 0);
            acc = __builtin_amdgcn_mfma_f32_16x16x32_bf16(wf[2 * d + 1], bfB, acc, 0, 0, 0);
        }

        float part = 0.f;
#pragma unroll
        for (int r = 0; r < 4; ++r)
            part = fmaf(w2v[r], fmaxf(acc[r] + b1v[r], 0.f), part);
        part += __shfl_xor(part, 16);
        part += __shfl_xor(part, 32);

        if (lane < 16 && p < 289) {
            float pre = part + b2v;
            float s = 1.f / (1.f + expf(-pre));
            s = fminf(fmaxf(s, 0.05f), 0.95f);
            out[((size_t)(b * 510 + h0 + pi)) * 510 + (w0 + pj)] = s;
        }
    }
}

extern "C" void kernel_launch(void* const* d_in, const int* in_sizes, int n_in,
                              void* d_out, int out_size, void* d_ws, size_t ws_size,
                              hipStream_t stream) {
    const float* x       = (const float*)d_in[0];
    const float* sobel_w = (const float*)d_in[1];
    const float* w1      = (const float*)d_in[2];
    const float* b1      = (const float*)d_in[3];
    const float* w2      = (const float*)d_in[4];
    const float* b2      = (const float*)d_in[5];
    float* out = (float*)d_out;
    unsigned short* wtab = (unsigned short*)d_ws;   // 18*64*16 = 18432 B

    prep_w1<<<dim3(18), dim3(64), 0, stream>>>(w1, wtab);
    fasa_mfma<<<dim3(3600), dim3(NT), 0, stream>>>(x, sobel_w, wtab, b1, w2, b2, out);
}